// Round 1
// 5954.106 us; speedup vs baseline: 2.1346x; 2.1346x over previous
//
#include <hip/hip_runtime.h>

#define SEQ 4096
#define EMB 512
#define NHEAD 8
#define DH 64
#define NHASH 4
#define NBUCK 64      // buckets per hash
#define NCHUNK 256    // NHASH * NBUCK
#define BS 64         // bucket size

// ---------- helpers ----------
__device__ __forceinline__ float gelu_acc(float x) {
    float x3 = x * x * x;
    return 0.5f * x * (1.0f + tanhf(0.7978845608f * (x + 0.044715f * x3)));
}
__device__ __forceinline__ double gelu_acc(double x) {
    double x3 = x * x * x;
    return 0.5 * x * (1.0 + tanh(0.7978845608028654 * (x + 0.044715 * x3)));
}

// ---------- embedding: x = tok_emb[tokens] + pos_emb ----------
__global__ void embed_kernel(const int* __restrict__ tokens, const float* __restrict__ tok_emb,
                             const float* __restrict__ pos_emb, float* __restrict__ x1,
                             float* __restrict__ x2) {
    int s = blockIdx.x, tid = threadIdx.x;
    int tok = tokens[s];
    float2 a = ((const float2*)(tok_emb + (size_t)tok * EMB))[tid];
    float2 b = ((const float2*)(pos_emb + (size_t)s * EMB))[tid];
    float2 r; r.x = a.x + b.x; r.y = a.y + b.y;
    ((float2*)(x1 + (size_t)s * EMB))[tid] = r;
    ((float2*)(x2 + (size_t)s * EMB))[tid] = r;
}

// ---------- layernorm, double internal math ----------
__global__ void ln_kernel(const float* __restrict__ x, const float* __restrict__ g,
                          const float* __restrict__ b, float* __restrict__ y) {
    int s = blockIdx.x, tid = threadIdx.x;
    float2 v = ((const float2*)(x + (size_t)s * EMB))[tid];
    double sum = (double)v.x + (double)v.y;
#pragma unroll
    for (int o = 32; o >= 1; o >>= 1) sum += __shfl_xor(sum, o, 64);
    __shared__ double red[4];
    if ((tid & 63) == 0) red[tid >> 6] = sum;
    __syncthreads();
    double mean = (red[0] + red[1] + red[2] + red[3]) * (1.0 / 512.0);
    double dx = (double)v.x - mean, dy = (double)v.y - mean;
    double sq = dx * dx + dy * dy;
#pragma unroll
    for (int o = 32; o >= 1; o >>= 1) sq += __shfl_xor(sq, o, 64);
    __syncthreads();
    if ((tid & 63) == 0) red[tid >> 6] = sq;
    __syncthreads();
    double var = (red[0] + red[1] + red[2] + red[3]) * (1.0 / 512.0);
    double sc = 1.0 / sqrt(var + 1e-3);
    float2 gg = ((const float2*)g)[tid];
    float2 bb = ((const float2*)b)[tid];
    float2 o2;
    o2.x = (float)(dx * sc * (double)gg.x + (double)bb.x);
    o2.y = (float)(dy * sc * (double)gg.y + (double)bb.y);
    ((float2*)(y + (size_t)s * EMB))[tid] = o2;
}

// ---------- tiled GEMM, BM=128, BN in {64,128}, BK=16, 256 threads, ACC type ----------
// epilogue: C = maybe_resid + maybe_gelu(A@B + maybe_bias); HOUT remaps [M,512]->[8][M][64]
template <int BN, bool BIAS, bool RESID, bool GELU_, bool HOUT, typename ACC>
__launch_bounds__(256)
__global__ void gemm_kernel(const float* __restrict__ A, const float* __restrict__ B,
                            float* __restrict__ C, const float* __restrict__ bias,
                            const float* __restrict__ resid, int M, int N, int K) {
    constexpr int BM = 128, BK = 16;
    constexpr int NCG = BN / 64;  // 1 or 2 column groups
    __shared__ float As[BK][BM];
    __shared__ float Bs[BK][BN];
    int tid = threadIdx.x;
    int bm = blockIdx.y * BM, bn = blockIdx.x * BN;
    int tx = tid & 15, ty = tid >> 4;
    ACC acc[2][NCG][4][4];
#pragma unroll
    for (int i = 0; i < 2; i++)
#pragma unroll
        for (int j = 0; j < NCG; j++)
#pragma unroll
            for (int r = 0; r < 4; r++)
#pragma unroll
                for (int c = 0; c < 4; c++) acc[i][j][r][c] = (ACC)0;

    int arow = tid >> 2;           // 0..63
    int ak = (tid & 3) * 4;        // 0,4,8,12

    for (int k0 = 0; k0 < K; k0 += BK) {
        float4 a0 = *(const float4*)(A + (size_t)(bm + arow) * K + k0 + ak);
        float4 a1 = *(const float4*)(A + (size_t)(bm + arow + 64) * K + k0 + ak);
        float4 b0, b1;
        if (BN == 64) {
            b0 = *(const float4*)(B + (size_t)(k0 + (tid >> 4)) * N + bn + (tid & 15) * 4);
        } else {
            b0 = *(const float4*)(B + (size_t)(k0 + (tid >> 5)) * N + bn + (tid & 31) * 4);
            b1 = *(const float4*)(B + (size_t)(k0 + (tid >> 5) + 8) * N + bn + (tid & 31) * 4);
        }
        __syncthreads();
        As[ak + 0][arow] = a0.x; As[ak + 1][arow] = a0.y; As[ak + 2][arow] = a0.z; As[ak + 3][arow] = a0.w;
        As[ak + 0][arow + 64] = a1.x; As[ak + 1][arow + 64] = a1.y; As[ak + 2][arow + 64] = a1.z; As[ak + 3][arow + 64] = a1.w;
        if (BN == 64) {
            *(float4*)&Bs[tid >> 4][(tid & 15) * 4] = b0;
        } else {
            *(float4*)&Bs[tid >> 5][(tid & 31) * 4] = b0;
            *(float4*)&Bs[(tid >> 5) + 8][(tid & 31) * 4] = b1;
        }
        __syncthreads();
#pragma unroll
        for (int kk = 0; kk < BK; kk++) {
            float av0[4], av1[4], bv0[4], bv1[4];
            *(float4*)av0 = *(const float4*)&As[kk][ty * 4];
            *(float4*)av1 = *(const float4*)&As[kk][ty * 4 + 64];
            *(float4*)bv0 = *(const float4*)&Bs[kk][tx * 4];
            if (NCG == 2) *(float4*)bv1 = *(const float4*)&Bs[kk][tx * 4 + 64];
            ACC ad0[4], ad1[4], bd0[4], bd1[4];
#pragma unroll
            for (int i = 0; i < 4; i++) {
                ad0[i] = (ACC)av0[i]; ad1[i] = (ACC)av1[i];
                bd0[i] = (ACC)bv0[i];
                if (NCG == 2) bd1[i] = (ACC)bv1[i];
            }
#pragma unroll
            for (int r = 0; r < 4; r++)
#pragma unroll
                for (int c = 0; c < 4; c++) {
                    acc[0][0][r][c] += ad0[r] * bd0[c];
                    acc[1][0][r][c] += ad1[r] * bd0[c];
                    if (NCG == 2) {
                        acc[0][1][r][c] += ad0[r] * bd1[c];
                        acc[1][1][r][c] += ad1[r] * bd1[c];
                    }
                }
        }
    }
#pragma unroll
    for (int rg = 0; rg < 2; rg++)
#pragma unroll
        for (int r = 0; r < 4; r++) {
            int m = bm + rg * 64 + ty * 4 + r;
#pragma unroll
            for (int cg = 0; cg < NCG; cg++) {
                int n0 = bn + cg * 64 + tx * 4;
                ACC res[4];
#pragma unroll
                for (int c = 0; c < 4; c++) res[c] = acc[rg][cg][r][c];
                if (BIAS) {
                    float4 bb = *(const float4*)(bias + n0);
                    res[0] += (ACC)bb.x; res[1] += (ACC)bb.y; res[2] += (ACC)bb.z; res[3] += (ACC)bb.w;
                }
                if (GELU_) {
#pragma unroll
                    for (int c = 0; c < 4; c++) res[c] = gelu_acc(res[c]);
                }
                if (RESID) {
                    float4 rr = *(const float4*)(resid + (size_t)m * N + n0);
                    res[0] += (ACC)rr.x; res[1] += (ACC)rr.y; res[2] += (ACC)rr.z; res[3] += (ACC)rr.w;
                }
                float4 fo;
                fo.x = (float)res[0]; fo.y = (float)res[1]; fo.z = (float)res[2]; fo.w = (float)res[3];
                if (HOUT) {
                    int hh = n0 >> 6, dd = n0 & 63;
                    *(float4*)(C + ((size_t)hh * SEQ + m) * DH + dd) = fo;
                } else {
                    *(float4*)(C + (size_t)m * N + n0) = fo;
                }
            }
        }
}

// ---------- k normalization: kn = qk / sqrt(sum(qk^2)+1e-12), double internal ----------
__global__ void knorm_kernel(const float* __restrict__ qk, float* __restrict__ kn) {
    int row = blockIdx.x * 4 + (threadIdx.x >> 6);
    int lane = threadIdx.x & 63;
    float v = qk[(size_t)row * DH + lane];
    double s = (double)v * (double)v;
#pragma unroll
    for (int o = 32; o >= 1; o >>= 1) s += __shfl_xor(s, o, 64);
    kn[(size_t)row * DH + lane] = (float)((double)v * (1.0 / sqrt(s + 1e-12)));
}

// ---------- LSH bucketing: GEMM-style [64 pos][128 r] tile per block, in-register argmax ----------
// rotated[s][r] = sum_dd qk[s][dd] * rot[dd][r]; bucket = argmax over [rotated, -rotated]
// grid: (SEQ/64, NHEAD), 256 threads. acc[4][8] double, fully static indexing (no scratch).
__launch_bounds__(256)
__global__ void bucket_kernel(const float* __restrict__ qk, const float* __restrict__ rot,
                              int* __restrict__ buckets) {
    __shared__ float qT[64 * 64];    // [dd][i]  (i = local pos)
    __shared__ float rs[64 * 128];   // [dd][h*32+r]
    int tid = threadIdx.x;
    int head = blockIdx.y;
    int s0 = blockIdx.x * 64;

    {   // stage rot (contiguous 8192 floats), vectorized
        const float4* rsrc = (const float4*)rot;
        float4* rdst = (float4*)rs;
#pragma unroll
        for (int j = 0; j < 8; j++) rdst[tid + j * 256] = rsrc[tid + j * 256];
    }
    {   // stage q transposed
        int i = tid >> 2, qu = tid & 3;
        const float4* src = (const float4*)(qk + ((size_t)head * SEQ + s0 + i) * DH + qu * 16);
#pragma unroll
        for (int j = 0; j < 4; j++) {
            float4 f = src[j];
            int dd = qu * 16 + j * 4;
            qT[(dd + 0) * 64 + i] = f.x; qT[(dd + 1) * 64 + i] = f.y;
            qT[(dd + 2) * 64 + i] = f.z; qT[(dd + 3) * 64 + i] = f.w;
        }
    }
    __syncthreads();

    int tx = tid & 15, ty = tid >> 4;
    double acc[4][8];
#pragma unroll
    for (int r = 0; r < 4; r++)
#pragma unroll
        for (int c = 0; c < 8; c++) acc[r][c] = 0.0;
    for (int dd = 0; dd < 64; dd++) {
        float qv[4], rv[8];
        *(float4*)qv = *(const float4*)&qT[dd * 64 + ty * 4];
        *(float4*)rv = *(const float4*)&rs[dd * 128 + tx * 4];
        *(float4*)(rv + 4) = *(const float4*)&rs[dd * 128 + 64 + tx * 4];
#pragma unroll
        for (int r = 0; r < 4; r++)
#pragma unroll
            for (int c = 0; c < 8; c++) acc[r][c] += (double)qv[r] * (double)rv[c];
    }

    // argmax per (pos, hash). Lane holds rcols {tx*4..tx*4+3} (hash = tx<8 ? 0 : 1)
    // and {64+tx*4..} (hash = tx<8 ? 2 : 3). j-in-hash = (tx&7)*4+c (positive) / +32 (negated).
    // First-max-wins: ascending-j strict '>' locally, tie-break smaller j across lanes.
    int txm = tx & 7;
    int hbit = (tx >> 3) & 1;
#pragma unroll
    for (int r = 0; r < 4; r++) {
#pragma unroll
        for (int g = 0; g < 2; g++) {
            double bv = acc[r][g * 4 + 0];
            int bj = txm * 4;
#pragma unroll
            for (int c = 1; c < 4; c++) {
                double v = acc[r][g * 4 + c];
                if (v > bv) { bv = v; bj = txm * 4 + c; }
            }
#pragma unroll
            for (int c = 0; c < 4; c++) {
                double v = -acc[r][g * 4 + c];
                if (v > bv) { bv = v; bj = 32 + txm * 4 + c; }
            }
#pragma unroll
            for (int o = 1; o <= 4; o <<= 1) {
                double ov = __shfl_xor(bv, o, 64);
                int oj = __shfl_xor(bj, o, 64);
                if (ov > bv || (ov == bv && oj < bj)) { bv = ov; bj = oj; }
            }
            if (txm == 0) {
                int h = (g << 1) | hbit;
                int s = s0 + ty * 4 + r;
                buckets[head * (NHASH * SEQ) + h * SEQ + s] = h * NBUCK + bj;
            }
        }
    }
}

// ---------- counting sort (== stable argsort of S*bucket + s) ----------
__global__ void hist_zero_kernel(int* __restrict__ hist) {
    hist[blockIdx.x * 256 + threadIdx.x] = 0;
}
__global__ void hist_kernel(const int* __restrict__ buckets, int* __restrict__ hist) {
    int i = blockIdx.x * 256 + threadIdx.x;  // 8*16384 items
    int head = i >> 14;
    atomicAdd(&hist[head * 256 + buckets[i]], 1);
}
__global__ void prefix_kernel(int* __restrict__ hist) {
    int head = threadIdx.x;
    if (head < NHEAD) {
        int run = 0;
        for (int c = 0; c < 256; c++) {
            int t = hist[head * 256 + c];
            hist[head * 256 + c] = run;
            run += t;
        }
    }
}
__global__ void scatter_kernel(const int* __restrict__ buckets, const int* __restrict__ hist,
                               int* __restrict__ sorted_t) {
    int head = blockIdx.x >> 8, c = blockIdx.x & 255;
    int h = c >> 6;
    int base = hist[head * 256 + c];
    const int* brow = buckets + head * (NHASH * SEQ) + h * SEQ;
    int lane = threadIdx.x;
    int cnt = 0;
    for (int s0 = 0; s0 < SEQ; s0 += 64) {
        int s = s0 + lane;
        bool f = (brow[s] == c);
        unsigned long long m = __ballot(f);
        if (f) {
            int rank = __popcll(m & ((1ull << lane) - 1ull));
            sorted_t[head * (NHASH * SEQ) + base + cnt + rank] = h * SEQ + s;
        }
        cnt += __popcll(m);
    }
}

// ---------- bucketed attention: one block per (chunk, head), fp32 LDS, fp64 accum ----------
// 64KB LDS phase overlay: A) qT[64][64]@0, kT[64][128]@4096, posq@12288, posk@12352
//                         B) pS[64][128]@0, vS[128][64]@8192
__launch_bounds__(256)
__global__ void attn_kernel(const float* __restrict__ qk, const float* __restrict__ kn,
                            const float* __restrict__ vv, const int* __restrict__ sorted_t,
                            float* __restrict__ o_uns, float* __restrict__ logit_uns) {
    __shared__ float buf[16384];  // 64 KB
    float* qT = buf;                  // [dd][i]  : dd*64 + i
    float* kT = buf + 4096;           // [dd][c]  : dd*128 + c
    int*   posq = (int*)(buf + 12288);  // 64
    int*   posk = (int*)(buf + 12352);  // 128
    float* pS = buf;                  // [i][c]   : i*128 + c
    float* vS = buf + 8192;           // [c][dd]  : c*64 + dd

    int chunk = blockIdx.x, head = blockIdx.y;
    int tid = threadIdx.x;
    const int* stp = sorted_t + head * (NHASH * SEQ);
    if (tid < 64) {
        posq[tid] = stp[chunk * BS + tid] & (SEQ - 1);
    } else if (tid < 192) {
        int c = tid - 64;
        int cc = (c < 64) ? chunk : (chunk + NCHUNK - 1) & (NCHUNK - 1);
        posk[c] = stp[cc * BS + (c & 63)] & (SEQ - 1);
    }
    __syncthreads();
    {   // stage q (transposed)
        int i = tid >> 2, qu = tid & 3;
        const float4* src = (const float4*)(qk + ((size_t)head * SEQ + posq[i]) * DH + qu * 16);
#pragma unroll
        for (int j = 0; j < 4; j++) {
            float4 f = src[j];
            int dd = qu * 16 + j * 4;
            qT[(dd + 0) * 64 + i] = f.x; qT[(dd + 1) * 64 + i] = f.y;
            qT[(dd + 2) * 64 + i] = f.z; qT[(dd + 3) * 64 + i] = f.w;
        }
    }
    {   // stage k (transposed)
        int c = tid >> 1, hf = tid & 1;
        const float4* ks = (const float4*)(kn + ((size_t)head * SEQ + posk[c]) * DH + hf * 32);
#pragma unroll
        for (int j = 0; j < 8; j++) {
            float4 f = ks[j];
            int dd = hf * 32 + j * 4;
            kT[(dd + 0) * 128 + c] = f.x; kT[(dd + 1) * 128 + c] = f.y;
            kT[(dd + 2) * 128 + c] = f.z; kT[(dd + 3) * 128 + c] = f.w;
        }
    }
    __syncthreads();

    int tx = tid & 15, ty = tid >> 4;
    double acc[4][8];
#pragma unroll
    for (int r = 0; r < 4; r++)
#pragma unroll
        for (int c = 0; c < 8; c++) acc[r][c] = 0.0;
    for (int dd = 0; dd < 64; dd++) {
        float qv[4], kv[8];
        *(float4*)qv = *(const float4*)&qT[dd * 64 + ty * 4];
        *(float4*)(kv) = *(const float4*)&kT[dd * 128 + tx * 4];
        *(float4*)(kv + 4) = *(const float4*)&kT[dd * 128 + 64 + tx * 4];
#pragma unroll
        for (int r = 0; r < 4; r++)
#pragma unroll
            for (int c = 0; c < 8; c++) acc[r][c] += (double)qv[r] * (double)kv[c];
    }
    // scale, self-mask, softmax per row across the 16 tx lanes (double)
    double lse_r[4];
#pragma unroll
    for (int r = 0; r < 4; r++) {
        int qp = posq[ty * 4 + r];
        double mx = -1.0e300;
#pragma unroll
        for (int c = 0; c < 8; c++) {
            int col = (c < 4) ? tx * 4 + c : 64 + tx * 4 + (c - 4);
            double dv = acc[r][c] * 0.125;
            if (posk[col] == qp) dv = -5.0e4;
            acc[r][c] = dv;
            mx = fmax(mx, dv);
        }
#pragma unroll
        for (int o = 1; o < 16; o <<= 1) mx = fmax(mx, __shfl_xor(mx, o, 64));
        double se = 0.0;
#pragma unroll
        for (int c = 0; c < 8; c++) {
            acc[r][c] = exp(acc[r][c] - mx);
            se += acc[r][c];
        }
#pragma unroll
        for (int o = 1; o < 16; o <<= 1) se += __shfl_xor(se, o, 64);
        double inv = 1.0 / se;
        lse_r[r] = mx + log(se);
#pragma unroll
        for (int c = 0; c < 8; c++) acc[r][c] *= inv;
    }
    // read my v-row index before overlay destroys posk
    int c2 = tid >> 1, hf2 = tid & 1;
    int mypk = posk[c2];
    __syncthreads();   // phase A fully read
    // write probs pS[i][c] and stage vS[c][dd]
#pragma unroll
    for (int r = 0; r < 4; r++) {
        int i = ty * 4 + r;
#pragma unroll
        for (int c = 0; c < 4; c++) {
            pS[i * 128 + tx * 4 + c] = (float)acc[r][c];
            pS[i * 128 + 64 + tx * 4 + c] = (float)acc[r][c + 4];
        }
    }
    {
        const float4* vsrc = (const float4*)(vv + ((size_t)head * SEQ + mypk) * DH + hf2 * 32);
#pragma unroll
        for (int j = 0; j < 8; j++) {
            *(float4*)&vS[c2 * 64 + hf2 * 32 + j * 4] = vsrc[j];
        }
    }
    __syncthreads();

    // PV: out[i][dd] = sum_c p[i][c] * v[c][dd]; rows ty*4..+3, cols tx*4..+3 (double accum)
    double outd[4][4];
#pragma unroll
    for (int r = 0; r < 4; r++)
#pragma unroll
        for (int j = 0; j < 4; j++) outd[r][j] = 0.0;
    for (int c = 0; c < 128; c++) {
        float pv[4], vv4[4];
#pragma unroll
        for (int r = 0; r < 4; r++) pv[r] = pS[(ty * 4 + r) * 128 + c];
        *(float4*)vv4 = *(const float4*)&vS[c * 64 + tx * 4];
#pragma unroll
        for (int r = 0; r < 4; r++)
#pragma unroll
            for (int j = 0; j < 4; j++) outd[r][j] += (double)pv[r] * (double)vv4[j];
    }
#pragma unroll
    for (int r = 0; r < 4; r++) {
        int t = stp[chunk * BS + ty * 4 + r];
        float4 o4;
        o4.x = (float)outd[r][0]; o4.y = (float)outd[r][1];
        o4.z = (float)outd[r][2]; o4.w = (float)outd[r][3];
        *(float4*)(o_uns + ((size_t)head * (NHASH * SEQ) + t) * DH + tx * 4) = o4;
        if (tx == 0) logit_uns[head * (NHASH * SEQ) + t] = (float)lse_r[r];
    }
}

// ---------- combine hash rounds: softmax over per-round LSEs (double) ----------
__global__ void combine_kernel(const float* __restrict__ o_uns, const float* __restrict__ logit_uns,
                               float* __restrict__ attn_out) {
    int idx = blockIdx.x * 4 + (threadIdx.x >> 6);  // head*SEQ + s
    int lane = threadIdx.x & 63;
    int head = idx >> 12, s = idx & 4095;
    double l[NHASH];
    double mx = -1.0e300;
#pragma unroll
    for (int h = 0; h < NHASH; h++) {
        l[h] = (double)logit_uns[head * (NHASH * SEQ) + h * SEQ + s];
        mx = fmax(mx, l[h]);
    }
    double se = 0.0;
#pragma unroll
    for (int h = 0; h < NHASH; h++) { l[h] = exp(l[h] - mx); se += l[h]; }
    double inv = 1.0 / se;
    double o = 0.0;
#pragma unroll
    for (int h = 0; h < NHASH; h++) {
        double w = l[h] * inv;
        o += (double)o_uns[((size_t)head * (NHASH * SEQ) + h * SEQ + s) * DH + lane] * w;
    }
    attn_out[(size_t)s * EMB + head * DH + lane] = (float)o;
}

// ---------- elementwise add ----------
__global__ void add_kernel(const float* __restrict__ a, const float* __restrict__ b,
                           float* __restrict__ c) {
    int i = blockIdx.x * 256 + threadIdx.x;
    float4 av = ((const float4*)a)[i];
    float4 bv = ((const float4*)b)[i];
    float4 cv; cv.x = av.x + bv.x; cv.y = av.y + bv.y; cv.z = av.z + bv.z; cv.w = av.w + bv.w;
    ((float4*)c)[i] = cv;
}

extern "C" void kernel_launch(void* const* d_in, const int* in_sizes, int n_in,
                              void* d_out, int out_size, void* d_ws, size_t ws_size,
                              hipStream_t stream) {
    const int*   tokens  = (const int*)d_in[0];
    const float* tok_emb = (const float*)d_in[1];
    const float* pos_emb = (const float*)d_in[2];
    const float* ln_f_g  = (const float*)d_in[3];
    const float* ln_f_b  = (const float*)d_in[4];
    const float* Wqk     = (const float*)d_in[5];
    const float* Wv      = (const float*)d_in[6];
    const float* Wo      = (const float*)d_in[7];
    const float* bo      = (const float*)d_in[8];
    const float* ln_g_g  = (const float*)d_in[9];
    const float* ln_g_b  = (const float*)d_in[10];
    const float* W1      = (const float*)d_in[11];
    const float* b1      = (const float*)d_in[12];
    const float* W2      = (const float*)d_in[13];
    const float* b2      = (const float*)d_in[14];
    const float* rots    = (const float*)d_in[15];
    const float* Wl      = (const float*)d_in[16];
    const float* bl      = (const float*)d_in[17];
    float* out = (float*)d_out;

    float* ws = (float*)d_ws;
    const size_t T = (size_t)SEQ * EMB;        // 2097152
    float* x1     = ws;
    float* x2     = ws + T;
    float* xn     = ws + 2 * T;
    float* qk     = ws + 3 * T;
    float* vbuf   = ws + 4 * T;
    float* knb    = ws + 5 * T;
    float* attn   = ws + 6 * T;
    float* big    = ws + 7 * T;                // 8388608 floats (hbuf / o_uns share)
    float* logitu = ws + 7 * T + 8388608;      // 131072 floats
    int*   buckets = (int*)(logitu + 131072);  // 131072 ints
    int*   sortedt = buckets + 131072;         // 131072 ints
    int*   hist    = sortedt + 131072;         // 2048 ints

    embed_kernel<<<SEQ, 256, 0, stream>>>(tokens, tok_emb, pos_emb, x1, x2);

    for (int d = 0; d < 4; d++) {
        const float* Wqk_d = Wqk + (size_t)d * EMB * EMB;
        const float* Wv_d  = Wv  + (size_t)d * EMB * EMB;
        const float* Wo_d  = Wo  + (size_t)d * EMB * EMB;
        const float* W1_d  = W1  + (size_t)d * EMB * 2048;
        const float* W2_d  = W2  + (size_t)d * 2048 * EMB;

        ln_kernel<<<SEQ, 256, 0, stream>>>(x2, ln_f_g + d * EMB, ln_f_b + d * EMB, xn);
        gemm_kernel<64, false, false, false, true, double><<<dim3(8, 32), 256, 0, stream>>>(
            xn, Wqk_d, qk, nullptr, nullptr, SEQ, EMB, EMB);
        gemm_kernel<64, false, false, false, true, double><<<dim3(8, 32), 256, 0, stream>>>(
            xn, Wv_d, vbuf, nullptr, nullptr, SEQ, EMB, EMB);
        knorm_kernel<<<NHEAD * SEQ / 4, 256, 0, stream>>>(qk, knb);
        bucket_kernel<<<dim3(SEQ / 64, NHEAD), 256, 0, stream>>>(qk, rots + d * 8192, buckets);
        hist_zero_kernel<<<NHEAD, 256, 0, stream>>>(hist);
        hist_kernel<<<NHEAD * NHASH * SEQ / 256, 256, 0, stream>>>(buckets, hist);
        prefix_kernel<<<1, 64, 0, stream>>>(hist);
        scatter_kernel<<<NHEAD * 256, 64, 0, stream>>>(buckets, hist, sortedt);
        attn_kernel<<<dim3(NCHUNK, NHEAD), 256, 0, stream>>>(qk, knb, vbuf, sortedt, big, logitu);
        combine_kernel<<<NHEAD * SEQ / 4, 256, 0, stream>>>(big, logitu, attn);
        gemm_kernel<64, true, true, false, false, double><<<dim3(8, 32), 256, 0, stream>>>(
            attn, Wo_d, x1, bo + d * EMB, x1, SEQ, EMB, EMB);   // y1 = x1 + attn_out
        ln_kernel<<<SEQ, 256, 0, stream>>>(x1, ln_g_g + d * EMB, ln_g_b + d * EMB, xn);
        gemm_kernel<64, true, false, true, false, double><<<dim3(32, 32), 256, 0, stream>>>(
            xn, W1_d, big, b1 + d * 2048, nullptr, SEQ, 2048, EMB);  // gelu(xn@W1+b1)
        gemm_kernel<64, true, true, false, false, double><<<dim3(8, 32), 256, 0, stream>>>(
            big, W2_d, x2, b2 + d * EMB, x2, SEQ, EMB, 2048);   // y2 = x2 + ff
    }

    add_kernel<<<T / 4 / 256, 256, 0, stream>>>(x1, x2, xn);
    gemm_kernel<128, true, false, false, false, float><<<dim3(250, 32), 256, 0, stream>>>(
        xn, Wl, out, bl, nullptr, SEQ, 32000, EMB);
}

// Round 2
// 4271.729 us; speedup vs baseline: 2.9753x; 1.3938x over previous
//
#include <hip/hip_runtime.h>

#define SEQ 4096
#define EMB 512
#define NHEAD 8
#define DH 64
#define NHASH 4
#define NBUCK 64      // buckets per hash
#define NCHUNK 256    // NHASH * NBUCK
#define BS 64         // bucket size

// ---------- helpers ----------
__device__ __forceinline__ float gelu_acc(float x) {
    float x3 = x * x * x;
    return 0.5f * x * (1.0f + tanhf(0.7978845608f * (x + 0.044715f * x3)));
}
__device__ __forceinline__ double gelu_acc(double x) {
    double x3 = x * x * x;
    return 0.5 * x * (1.0 + tanh(0.7978845608028654 * (x + 0.044715 * x3)));
}

// ---------- embedding: x = tok_emb[tokens] + pos_emb ----------
__global__ void embed_kernel(const int* __restrict__ tokens, const float* __restrict__ tok_emb,
                             const float* __restrict__ pos_emb, float* __restrict__ x1,
                             float* __restrict__ x2) {
    int s = blockIdx.x, tid = threadIdx.x;
    int tok = tokens[s];
    float2 a = ((const float2*)(tok_emb + (size_t)tok * EMB))[tid];
    float2 b = ((const float2*)(pos_emb + (size_t)s * EMB))[tid];
    float2 r; r.x = a.x + b.x; r.y = a.y + b.y;
    ((float2*)(x1 + (size_t)s * EMB))[tid] = r;
    ((float2*)(x2 + (size_t)s * EMB))[tid] = r;
}

// ---------- layernorm, double internal math (bucket-critical path) ----------
__global__ void ln_kernel(const float* __restrict__ x, const float* __restrict__ g,
                          const float* __restrict__ b, float* __restrict__ y) {
    int s = blockIdx.x, tid = threadIdx.x;
    float2 v = ((const float2*)(x + (size_t)s * EMB))[tid];
    double sum = (double)v.x + (double)v.y;
#pragma unroll
    for (int o = 32; o >= 1; o >>= 1) sum += __shfl_xor(sum, o, 64);
    __shared__ double red[4];
    if ((tid & 63) == 0) red[tid >> 6] = sum;
    __syncthreads();
    double mean = (red[0] + red[1] + red[2] + red[3]) * (1.0 / 512.0);
    double dx = (double)v.x - mean, dy = (double)v.y - mean;
    double sq = dx * dx + dy * dy;
#pragma unroll
    for (int o = 32; o >= 1; o >>= 1) sq += __shfl_xor(sq, o, 64);
    __syncthreads();
    if ((tid & 63) == 0) red[tid >> 6] = sq;
    __syncthreads();
    double var = (red[0] + red[1] + red[2] + red[3]) * (1.0 / 512.0);
    double sc = 1.0 / sqrt(var + 1e-3);
    float2 gg = ((const float2*)g)[tid];
    float2 bb = ((const float2*)b)[tid];
    float2 o2;
    o2.x = (float)(dx * sc * (double)gg.x + (double)bb.x);
    o2.y = (float)(dy * sc * (double)gg.y + (double)bb.y);
    ((float2*)(y + (size_t)s * EMB))[tid] = o2;
}

// ---------- tiled GEMM, BM=128, BN in {64,128}, BK=16, 256 threads, ACC type ----------
// Software-pipelined: next K-tile prefetched into regs during compute (vmem hides under FMA).
// epilogue: C = maybe_resid + maybe_gelu(A@B + maybe_bias); HOUT remaps [M,512]->[8][M][64]
template <int BN, bool BIAS, bool RESID, bool GELU_, bool HOUT, typename ACC>
__launch_bounds__(256)
__global__ void gemm_kernel(const float* __restrict__ A, const float* __restrict__ B,
                            float* __restrict__ C, const float* __restrict__ bias,
                            const float* __restrict__ resid, int M, int N, int K) {
    constexpr int BM = 128, BK = 16;
    constexpr int NCG = BN / 64;  // 1 or 2 column groups
    __shared__ float As[BK][BM];
    __shared__ float Bs[BK][BN];
    int tid = threadIdx.x;
    int bm = blockIdx.y * BM, bn = blockIdx.x * BN;
    int tx = tid & 15, ty = tid >> 4;
    ACC acc[2][NCG][4][4];
#pragma unroll
    for (int i = 0; i < 2; i++)
#pragma unroll
        for (int j = 0; j < NCG; j++)
#pragma unroll
            for (int r = 0; r < 4; r++)
#pragma unroll
                for (int c = 0; c < 4; c++) acc[i][j][r][c] = (ACC)0;

    int arow = tid >> 2;           // 0..63
    int ak = (tid & 3) * 4;        // 0,4,8,12

    // prologue: load tile k0=0 into regs
    float4 a0 = *(const float4*)(A + (size_t)(bm + arow) * K + ak);
    float4 a1 = *(const float4*)(A + (size_t)(bm + arow + 64) * K + ak);
    float4 b0, b1;
    if (BN == 64) {
        b0 = *(const float4*)(B + (size_t)(tid >> 4) * N + bn + (tid & 15) * 4);
    } else {
        b0 = *(const float4*)(B + (size_t)(tid >> 5) * N + bn + (tid & 31) * 4);
        b1 = *(const float4*)(B + (size_t)((tid >> 5) + 8) * N + bn + (tid & 31) * 4);
    }

    for (int k0 = 0; k0 < K; k0 += BK) {
        __syncthreads();
        As[ak + 0][arow] = a0.x; As[ak + 1][arow] = a0.y; As[ak + 2][arow] = a0.z; As[ak + 3][arow] = a0.w;
        As[ak + 0][arow + 64] = a1.x; As[ak + 1][arow + 64] = a1.y; As[ak + 2][arow + 64] = a1.z; As[ak + 3][arow + 64] = a1.w;
        if (BN == 64) {
            *(float4*)&Bs[tid >> 4][(tid & 15) * 4] = b0;
        } else {
            *(float4*)&Bs[tid >> 5][(tid & 31) * 4] = b0;
            *(float4*)&Bs[(tid >> 5) + 8][(tid & 31) * 4] = b1;
        }
        __syncthreads();
        // prefetch next tile (latency hides under FMA block below)
        float4 na0, na1, nb0, nb1;
        bool more = (k0 + BK) < K;
        if (more) {
            int kn_ = k0 + BK;
            na0 = *(const float4*)(A + (size_t)(bm + arow) * K + kn_ + ak);
            na1 = *(const float4*)(A + (size_t)(bm + arow + 64) * K + kn_ + ak);
            if (BN == 64) {
                nb0 = *(const float4*)(B + (size_t)(kn_ + (tid >> 4)) * N + bn + (tid & 15) * 4);
            } else {
                nb0 = *(const float4*)(B + (size_t)(kn_ + (tid >> 5)) * N + bn + (tid & 31) * 4);
                nb1 = *(const float4*)(B + (size_t)(kn_ + (tid >> 5) + 8) * N + bn + (tid & 31) * 4);
            }
        }
#pragma unroll
        for (int kk = 0; kk < BK; kk++) {
            float av0[4], av1[4], bv0[4], bv1[4];
            *(float4*)av0 = *(const float4*)&As[kk][ty * 4];
            *(float4*)av1 = *(const float4*)&As[kk][ty * 4 + 64];
            *(float4*)bv0 = *(const float4*)&Bs[kk][tx * 4];
            if (NCG == 2) *(float4*)bv1 = *(const float4*)&Bs[kk][tx * 4 + 64];
            ACC ad0[4], ad1[4], bd0[4], bd1[4];
#pragma unroll
            for (int i = 0; i < 4; i++) {
                ad0[i] = (ACC)av0[i]; ad1[i] = (ACC)av1[i];
                bd0[i] = (ACC)bv0[i];
                if (NCG == 2) bd1[i] = (ACC)bv1[i];
            }
#pragma unroll
            for (int r = 0; r < 4; r++)
#pragma unroll
                for (int c = 0; c < 4; c++) {
                    acc[0][0][r][c] += ad0[r] * bd0[c];
                    acc[1][0][r][c] += ad1[r] * bd0[c];
                    if (NCG == 2) {
                        acc[0][1][r][c] += ad0[r] * bd1[c];
                        acc[1][1][r][c] += ad1[r] * bd1[c];
                    }
                }
        }
        if (more) { a0 = na0; a1 = na1; b0 = nb0; if (BN == 128) b1 = nb1; }
    }
#pragma unroll
    for (int rg = 0; rg < 2; rg++)
#pragma unroll
        for (int r = 0; r < 4; r++) {
            int m = bm + rg * 64 + ty * 4 + r;
#pragma unroll
            for (int cg = 0; cg < NCG; cg++) {
                int n0 = bn + cg * 64 + tx * 4;
                ACC res[4];
#pragma unroll
                for (int c = 0; c < 4; c++) res[c] = acc[rg][cg][r][c];
                if (BIAS) {
                    float4 bb = *(const float4*)(bias + n0);
                    res[0] += (ACC)bb.x; res[1] += (ACC)bb.y; res[2] += (ACC)bb.z; res[3] += (ACC)bb.w;
                }
                if (GELU_) {
#pragma unroll
                    for (int c = 0; c < 4; c++) res[c] = gelu_acc(res[c]);
                }
                if (RESID) {
                    float4 rr = *(const float4*)(resid + (size_t)m * N + n0);
                    res[0] += (ACC)rr.x; res[1] += (ACC)rr.y; res[2] += (ACC)rr.z; res[3] += (ACC)rr.w;
                }
                float4 fo;
                fo.x = (float)res[0]; fo.y = (float)res[1]; fo.z = (float)res[2]; fo.w = (float)res[3];
                if (HOUT) {
                    int hh = n0 >> 6, dd = n0 & 63;
                    *(float4*)(C + ((size_t)hh * SEQ + m) * DH + dd) = fo;
                } else {
                    *(float4*)(C + (size_t)m * N + n0) = fo;
                }
            }
        }
}

// ---------- k normalization: kn = qk / sqrt(sum(qk^2)+1e-12), double internal ----------
__global__ void knorm_kernel(const float* __restrict__ qk, float* __restrict__ kn) {
    int row = blockIdx.x * 4 + (threadIdx.x >> 6);
    int lane = threadIdx.x & 63;
    float v = qk[(size_t)row * DH + lane];
    double s = (double)v * (double)v;
#pragma unroll
    for (int o = 32; o >= 1; o >>= 1) s += __shfl_xor(s, o, 64);
    kn[(size_t)row * DH + lane] = (float)((double)v * (1.0 / sqrt(s + 1e-12)));
}

// ---------- LSH bucketing: GEMM-style [64 pos][128 r] tile per block, in-register argmax ----------
// fp64 accumulation: bucket-critical path.
__launch_bounds__(256)
__global__ void bucket_kernel(const float* __restrict__ qk, const float* __restrict__ rot,
                              int* __restrict__ buckets) {
    __shared__ float qT[64 * 64];    // [dd][i]  (i = local pos)
    __shared__ float rs[64 * 128];   // [dd][h*32+r]
    int tid = threadIdx.x;
    int head = blockIdx.y;
    int s0 = blockIdx.x * 64;

    {   // stage rot (contiguous 8192 floats), vectorized
        const float4* rsrc = (const float4*)rot;
        float4* rdst = (float4*)rs;
#pragma unroll
        for (int j = 0; j < 8; j++) rdst[tid + j * 256] = rsrc[tid + j * 256];
    }
    {   // stage q transposed
        int i = tid >> 2, qu = tid & 3;
        const float4* src = (const float4*)(qk + ((size_t)head * SEQ + s0 + i) * DH + qu * 16);
#pragma unroll
        for (int j = 0; j < 4; j++) {
            float4 f = src[j];
            int dd = qu * 16 + j * 4;
            qT[(dd + 0) * 64 + i] = f.x; qT[(dd + 1) * 64 + i] = f.y;
            qT[(dd + 2) * 64 + i] = f.z; qT[(dd + 3) * 64 + i] = f.w;
        }
    }
    __syncthreads();

    int tx = tid & 15, ty = tid >> 4;
    double acc[4][8];
#pragma unroll
    for (int r = 0; r < 4; r++)
#pragma unroll
        for (int c = 0; c < 8; c++) acc[r][c] = 0.0;
    for (int dd = 0; dd < 64; dd++) {
        float qv[4], rv[8];
        *(float4*)qv = *(const float4*)&qT[dd * 64 + ty * 4];
        *(float4*)rv = *(const float4*)&rs[dd * 128 + tx * 4];
        *(float4*)(rv + 4) = *(const float4*)&rs[dd * 128 + 64 + tx * 4];
#pragma unroll
        for (int r = 0; r < 4; r++)
#pragma unroll
            for (int c = 0; c < 8; c++) acc[r][c] += (double)qv[r] * (double)rv[c];
    }

    int txm = tx & 7;
    int hbit = (tx >> 3) & 1;
#pragma unroll
    for (int r = 0; r < 4; r++) {
#pragma unroll
        for (int g = 0; g < 2; g++) {
            double bv = acc[r][g * 4 + 0];
            int bj = txm * 4;
#pragma unroll
            for (int c = 1; c < 4; c++) {
                double v = acc[r][g * 4 + c];
                if (v > bv) { bv = v; bj = txm * 4 + c; }
            }
#pragma unroll
            for (int c = 0; c < 4; c++) {
                double v = -acc[r][g * 4 + c];
                if (v > bv) { bv = v; bj = 32 + txm * 4 + c; }
            }
#pragma unroll
            for (int o = 1; o <= 4; o <<= 1) {
                double ov = __shfl_xor(bv, o, 64);
                int oj = __shfl_xor(bj, o, 64);
                if (ov > bv || (ov == bv && oj < bj)) { bv = ov; bj = oj; }
            }
            if (txm == 0) {
                int h = (g << 1) | hbit;
                int s = s0 + ty * 4 + r;
                buckets[head * (NHASH * SEQ) + h * SEQ + s] = h * NBUCK + bj;
            }
        }
    }
}

// ---------- counting sort (== stable argsort of S*bucket + s) ----------
__global__ void hist_zero_kernel(int* __restrict__ hist) {
    hist[blockIdx.x * 256 + threadIdx.x] = 0;
}
__global__ void hist_kernel(const int* __restrict__ buckets, int* __restrict__ hist) {
    int i = blockIdx.x * 256 + threadIdx.x;  // 8*16384 items
    int head = i >> 14;
    atomicAdd(&hist[head * 256 + buckets[i]], 1);
}
__global__ void prefix_kernel(int* __restrict__ hist) {
    int head = threadIdx.x;
    if (head < NHEAD) {
        int run = 0;
        for (int c = 0; c < 256; c++) {
            int t = hist[head * 256 + c];
            hist[head * 256 + c] = run;
            run += t;
        }
    }
}
__global__ void scatter_kernel(const int* __restrict__ buckets, const int* __restrict__ hist,
                               int* __restrict__ sorted_t) {
    int head = blockIdx.x >> 8, c = blockIdx.x & 255;
    int h = c >> 6;
    int base = hist[head * 256 + c];
    const int* brow = buckets + head * (NHASH * SEQ) + h * SEQ;
    int lane = threadIdx.x;
    int cnt = 0;
    for (int s0 = 0; s0 < SEQ; s0 += 64) {
        int s = s0 + lane;
        bool f = (brow[s] == c);
        unsigned long long m = __ballot(f);
        if (f) {
            int rank = __popcll(m & ((1ull << lane) - 1ull));
            sorted_t[head * (NHASH * SEQ) + base + cnt + rank] = h * SEQ + s;
        }
        cnt += __popcll(m);
    }
}

// ---------- bucketed attention: one block per (chunk, head), fp32 throughout ----------
// (off-bucket-path: smooth error propagation, hardware __expf/__logf)
// 64KB LDS phase overlay: A) qT[64][64]@0, kT[64][128]@4096, posq@12288, posk@12352
//                         B) pS[64][128]@0, vS[128][64]@8192
__launch_bounds__(256)
__global__ void attn_kernel(const float* __restrict__ qk, const float* __restrict__ kn,
                            const float* __restrict__ vv, const int* __restrict__ sorted_t,
                            float* __restrict__ o_uns, float* __restrict__ logit_uns) {
    __shared__ float buf[16384];  // 64 KB
    float* qT = buf;                  // [dd][i]  : dd*64 + i
    float* kT = buf + 4096;           // [dd][c]  : dd*128 + c
    int*   posq = (int*)(buf + 12288);  // 64
    int*   posk = (int*)(buf + 12352);  // 128
    float* pS = buf;                  // [i][c]   : i*128 + c
    float* vS = buf + 8192;           // [c][dd]  : c*64 + dd

    int chunk = blockIdx.x, head = blockIdx.y;
    int tid = threadIdx.x;
    const int* stp = sorted_t + head * (NHASH * SEQ);
    if (tid < 64) {
        posq[tid] = stp[chunk * BS + tid] & (SEQ - 1);
    } else if (tid < 192) {
        int c = tid - 64;
        int cc = (c < 64) ? chunk : (chunk + NCHUNK - 1) & (NCHUNK - 1);
        posk[c] = stp[cc * BS + (c & 63)] & (SEQ - 1);
    }
    __syncthreads();
    {   // stage q (transposed)
        int i = tid >> 2, qu = tid & 3;
        const float4* src = (const float4*)(qk + ((size_t)head * SEQ + posq[i]) * DH + qu * 16);
#pragma unroll
        for (int j = 0; j < 4; j++) {
            float4 f = src[j];
            int dd = qu * 16 + j * 4;
            qT[(dd + 0) * 64 + i] = f.x; qT[(dd + 1) * 64 + i] = f.y;
            qT[(dd + 2) * 64 + i] = f.z; qT[(dd + 3) * 64 + i] = f.w;
        }
    }
    {   // stage k (transposed)
        int c = tid >> 1, hf = tid & 1;
        const float4* ks = (const float4*)(kn + ((size_t)head * SEQ + posk[c]) * DH + hf * 32);
#pragma unroll
        for (int j = 0; j < 8; j++) {
            float4 f = ks[j];
            int dd = hf * 32 + j * 4;
            kT[(dd + 0) * 128 + c] = f.x; kT[(dd + 1) * 128 + c] = f.y;
            kT[(dd + 2) * 128 + c] = f.z; kT[(dd + 3) * 128 + c] = f.w;
        }
    }
    __syncthreads();

    int tx = tid & 15, ty = tid >> 4;
    float acc[4][8];
#pragma unroll
    for (int r = 0; r < 4; r++)
#pragma unroll
        for (int c = 0; c < 8; c++) acc[r][c] = 0.0f;
    for (int dd = 0; dd < 64; dd++) {
        float qv[4], kv[8];
        *(float4*)qv = *(const float4*)&qT[dd * 64 + ty * 4];
        *(float4*)(kv) = *(const float4*)&kT[dd * 128 + tx * 4];
        *(float4*)(kv + 4) = *(const float4*)&kT[dd * 128 + 64 + tx * 4];
#pragma unroll
        for (int r = 0; r < 4; r++)
#pragma unroll
            for (int c = 0; c < 8; c++) acc[r][c] += qv[r] * kv[c];
    }
    // scale, self-mask, softmax per row across the 16 tx lanes (fp32, hw exp/log)
    float lse_r[4];
#pragma unroll
    for (int r = 0; r < 4; r++) {
        int qp = posq[ty * 4 + r];
        float mx = -1.0e30f;
#pragma unroll
        for (int c = 0; c < 8; c++) {
            int col = (c < 4) ? tx * 4 + c : 64 + tx * 4 + (c - 4);
            float dv = acc[r][c] * 0.125f;
            if (posk[col] == qp) dv = -5.0e4f;
            acc[r][c] = dv;
            mx = fmaxf(mx, dv);
        }
#pragma unroll
        for (int o = 1; o < 16; o <<= 1) mx = fmaxf(mx, __shfl_xor(mx, o, 64));
        float se = 0.0f;
#pragma unroll
        for (int c = 0; c < 8; c++) {
            acc[r][c] = __expf(acc[r][c] - mx);
            se += acc[r][c];
        }
#pragma unroll
        for (int o = 1; o < 16; o <<= 1) se += __shfl_xor(se, o, 64);
        float inv = 1.0f / se;
        lse_r[r] = mx + __logf(se);
#pragma unroll
        for (int c = 0; c < 8; c++) acc[r][c] *= inv;
    }
    // read my v-row index before overlay destroys posk
    int c2 = tid >> 1, hf2 = tid & 1;
    int mypk = posk[c2];
    __syncthreads();   // phase A fully read
    // write probs pS[i][c] and stage vS[c][dd]
#pragma unroll
    for (int r = 0; r < 4; r++) {
        int i = ty * 4 + r;
#pragma unroll
        for (int c = 0; c < 4; c++) {
            pS[i * 128 + tx * 4 + c] = acc[r][c];
            pS[i * 128 + 64 + tx * 4 + c] = acc[r][c + 4];
        }
    }
    {
        const float4* vsrc = (const float4*)(vv + ((size_t)head * SEQ + mypk) * DH + hf2 * 32);
#pragma unroll
        for (int j = 0; j < 8; j++) {
            *(float4*)&vS[c2 * 64 + hf2 * 32 + j * 4] = vsrc[j];
        }
    }
    __syncthreads();

    // PV: out[i][dd] = sum_c p[i][c] * v[c][dd]; rows ty*4..+3, cols tx*4..+3 (fp32)
    float outd[4][4];
#pragma unroll
    for (int r = 0; r < 4; r++)
#pragma unroll
        for (int j = 0; j < 4; j++) outd[r][j] = 0.0f;
    for (int c = 0; c < 128; c++) {
        float pv[4], vv4[4];
#pragma unroll
        for (int r = 0; r < 4; r++) pv[r] = pS[(ty * 4 + r) * 128 + c];
        *(float4*)vv4 = *(const float4*)&vS[c * 64 + tx * 4];
#pragma unroll
        for (int r = 0; r < 4; r++)
#pragma unroll
            for (int j = 0; j < 4; j++) outd[r][j] += pv[r] * vv4[j];
    }
#pragma unroll
    for (int r = 0; r < 4; r++) {
        int t = stp[chunk * BS + ty * 4 + r];
        float4 o4;
        o4.x = outd[r][0]; o4.y = outd[r][1];
        o4.z = outd[r][2]; o4.w = outd[r][3];
        *(float4*)(o_uns + ((size_t)head * (NHASH * SEQ) + t) * DH + tx * 4) = o4;
        if (tx == 0) logit_uns[head * (NHASH * SEQ) + t] = lse_r[r];
    }
}

// ---------- combine hash rounds: softmax over per-round LSEs (fp32) ----------
__global__ void combine_kernel(const float* __restrict__ o_uns, const float* __restrict__ logit_uns,
                               float* __restrict__ attn_out) {
    int idx = blockIdx.x * 4 + (threadIdx.x >> 6);  // head*SEQ + s
    int lane = threadIdx.x & 63;
    int head = idx >> 12, s = idx & 4095;
    float l[NHASH];
    float mx = -1.0e30f;
#pragma unroll
    for (int h = 0; h < NHASH; h++) {
        l[h] = logit_uns[head * (NHASH * SEQ) + h * SEQ + s];
        mx = fmaxf(mx, l[h]);
    }
    float se = 0.0f;
#pragma unroll
    for (int h = 0; h < NHASH; h++) { l[h] = __expf(l[h] - mx); se += l[h]; }
    float inv = 1.0f / se;
    float o = 0.0f;
#pragma unroll
    for (int h = 0; h < NHASH; h++) {
        float w = l[h] * inv;
        o += o_uns[((size_t)head * (NHASH * SEQ) + h * SEQ + s) * DH + lane] * w;
    }
    attn_out[(size_t)s * EMB + head * DH + lane] = o;
}

// ---------- elementwise add ----------
__global__ void add_kernel(const float* __restrict__ a, const float* __restrict__ b,
                           float* __restrict__ c) {
    int i = blockIdx.x * 256 + threadIdx.x;
    float4 av = ((const float4*)a)[i];
    float4 bv = ((const float4*)b)[i];
    float4 cv; cv.x = av.x + bv.x; cv.y = av.y + bv.y; cv.z = av.z + bv.z; cv.w = av.w + bv.w;
    ((float4*)c)[i] = cv;
}

extern "C" void kernel_launch(void* const* d_in, const int* in_sizes, int n_in,
                              void* d_out, int out_size, void* d_ws, size_t ws_size,
                              hipStream_t stream) {
    const int*   tokens  = (const int*)d_in[0];
    const float* tok_emb = (const float*)d_in[1];
    const float* pos_emb = (const float*)d_in[2];
    const float* ln_f_g  = (const float*)d_in[3];
    const float* ln_f_b  = (const float*)d_in[4];
    const float* Wqk     = (const float*)d_in[5];
    const float* Wv      = (const float*)d_in[6];
    const float* Wo      = (const float*)d_in[7];
    const float* bo      = (const float*)d_in[8];
    const float* ln_g_g  = (const float*)d_in[9];
    const float* ln_g_b  = (const float*)d_in[10];
    const float* W1      = (const float*)d_in[11];
    const float* b1      = (const float*)d_in[12];
    const float* W2      = (const float*)d_in[13];
    const float* b2      = (const float*)d_in[14];
    const float* rots    = (const float*)d_in[15];
    const float* Wl      = (const float*)d_in[16];
    const float* bl      = (const float*)d_in[17];
    float* out = (float*)d_out;

    float* ws = (float*)d_ws;
    const size_t T = (size_t)SEQ * EMB;        // 2097152
    float* x1     = ws;
    float* x2     = ws + T;
    float* xn     = ws + 2 * T;
    float* qk     = ws + 3 * T;
    float* vbuf   = ws + 4 * T;
    float* knb    = ws + 5 * T;
    float* attn   = ws + 6 * T;
    float* big    = ws + 7 * T;                // 8388608 floats (hbuf / o_uns share)
    float* logitu = ws + 7 * T + 8388608;      // 131072 floats
    int*   buckets = (int*)(logitu + 131072);  // 131072 ints
    int*   sortedt = buckets + 131072;         // 131072 ints
    int*   hist    = sortedt + 131072;         // 2048 ints

    embed_kernel<<<SEQ, 256, 0, stream>>>(tokens, tok_emb, pos_emb, x1, x2);

    for (int d = 0; d < 4; d++) {
        const float* Wqk_d = Wqk + (size_t)d * EMB * EMB;
        const float* Wv_d  = Wv  + (size_t)d * EMB * EMB;
        const float* Wo_d  = Wo  + (size_t)d * EMB * EMB;
        const float* W1_d  = W1  + (size_t)d * EMB * 2048;
        const float* W2_d  = W2  + (size_t)d * 2048 * EMB;

        ln_kernel<<<SEQ, 256, 0, stream>>>(x2, ln_f_g + d * EMB, ln_f_b + d * EMB, xn);
        // qk projection: fp64 accumulate (feeds bucket argmax directly)
        gemm_kernel<64, false, false, false, true, double><<<dim3(8, 32), 256, 0, stream>>>(
            xn, Wqk_d, qk, nullptr, nullptr, SEQ, EMB, EMB);
        // v projection: fp32 accumulate (smooth path)
        gemm_kernel<64, false, false, false, true, float><<<dim3(8, 32), 256, 0, stream>>>(
            xn, Wv_d, vbuf, nullptr, nullptr, SEQ, EMB, EMB);
        knorm_kernel<<<NHEAD * SEQ / 4, 256, 0, stream>>>(qk, knb);
        bucket_kernel<<<dim3(SEQ / 64, NHEAD), 256, 0, stream>>>(qk, rots + d * 8192, buckets);
        hist_zero_kernel<<<NHEAD, 256, 0, stream>>>(hist);
        hist_kernel<<<NHEAD * NHASH * SEQ / 256, 256, 0, stream>>>(buckets, hist);
        prefix_kernel<<<1, 64, 0, stream>>>(hist);
        scatter_kernel<<<NHEAD * 256, 64, 0, stream>>>(buckets, hist, sortedt);
        attn_kernel<<<dim3(NCHUNK, NHEAD), 256, 0, stream>>>(qk, knb, vbuf, sortedt, big, logitu);
        combine_kernel<<<NHEAD * SEQ / 4, 256, 0, stream>>>(big, logitu, attn);
        gemm_kernel<64, true, true, false, false, float><<<dim3(8, 32), 256, 0, stream>>>(
            attn, Wo_d, x1, bo + d * EMB, x1, SEQ, EMB, EMB);   // y1 = x1 + attn_out
        ln_kernel<<<SEQ, 256, 0, stream>>>(x1, ln_g_g + d * EMB, ln_g_b + d * EMB, xn);
        gemm_kernel<64, true, false, true, false, float><<<dim3(32, 32), 256, 0, stream>>>(
            xn, W1_d, big, b1 + d * 2048, nullptr, SEQ, 2048, EMB);  // gelu(xn@W1+b1)
        gemm_kernel<64, true, true, false, false, float><<<dim3(8, 32), 256, 0, stream>>>(
            big, W2_d, x2, b2 + d * EMB, x2, SEQ, EMB, 2048);   // y2 = x2 + ff
    }

    add_kernel<<<T / 4 / 256, 256, 0, stream>>>(x1, x2, xn);
    gemm_kernel<128, true, false, false, false, float><<<dim3(250, 32), 256, 0, stream>>>(
        xn, Wl, out, bl, nullptr, SEQ, 32000, EMB);
}